// Round 5
// baseline (392.362 us; speedup 1.0000x reference)
//
#include <hip/hip_runtime.h>
#include <math.h>

#define HID 128
constexpr int Nn = 20000;
constexpr int Ee = 80000;
constexpr int Gg = 1000;

typedef _Float16 f16x8 __attribute__((ext_vector_type(8)));
typedef _Float16 f16x4 __attribute__((ext_vector_type(4)));
typedef _Float16 f16x2 __attribute__((ext_vector_type(2)));
typedef float    f32x4 __attribute__((ext_vector_type(4)));

__device__ __forceinline__ float eluf(float x){ return x > 0.f ? x : (expf(x) - 1.f); }

// h0 = x[:, :5]
__global__ void h0_kernel(const float* __restrict__ x, float* __restrict__ h){
  int idx = blockIdx.x * blockDim.x + threadIdx.x;
  if (idx >= Nn * 5) return;
  int n = idx / 5, c = idx - n * 5;
  h[idx] = x[(size_t)n * 16 + c];
}

// ---- B permute for MFMA edge GEMM (ks-major layout) ----
// bt[((ks*NF + n)*64 + l)*8 + j] = B[ks*32 + (l>>4)*8 + j][n*16 + (l&15)]
template<int MIR, int MIP, int MO, int HIDK>
__global__ void bt_kernel(const float* __restrict__ w2, const float* __restrict__ b2,
                          _Float16* __restrict__ bt){
  constexpr int KS = (HIDK * MIP) / 32;
  constexpr int NF = MO / 16;
  int idx = blockIdx.x * 256 + threadIdx.x;
  if (idx >= NF * KS * 512) return;
  int j  = idx & 7;
  int l  = (idx >> 3) & 63;
  int n  = (idx >> 9) % NF;
  int ks = idx / (NF * 512);
  int col = n * 16 + (l & 15);
  int kk  = ks * 32 + ((l >> 4) << 3) + j;
  int k = kk / MIP, i = kk % MIP;
  float v = 0.f;
  if (i < MIR){
    if (k < 128)       v = w2[(size_t)k * (MIR * MO) + i * MO + col];
    else if (k == 128) v = b2[i * MO + col];
  }
  bt[idx] = (_Float16)v;
}

// agg[n,o] = bias[o] + sum_i h[n,i]*root[i,o]
template<int MI, int MO>
__global__ void node_kernel(const float* __restrict__ h, const float* __restrict__ root,
                            const float* __restrict__ bias, float* __restrict__ agg){
  int idx = blockIdx.x * blockDim.x + threadIdx.x;
  if (idx >= Nn * MO) return;
  int n = idx / MO, o = idx - n * MO;
  float s = bias[o];
  #pragma unroll
  for (int i = 0; i < MI; ++i) s += h[(size_t)n * MI + i] * root[i * MO + o];
  agg[idx] = s;
}

// ---- MFMA edge kernel: 4 waves/WG, 128 edges/WG ----
// wave = (edge-half, col-half): 64 edges x MO/2 cols per wave.
// depth-4 B prefetch, A hoisted to registers, swizzled hs_lds.
template<int MIR, int MIP, int MO, int HIDK>
__global__ __launch_bounds__(256) void edge_mfma(
    const float* __restrict__ ea, const float* __restrict__ w1, const float* __restrict__ b1,
    const _Float16* __restrict__ bt, const float* __restrict__ h,
    const int* __restrict__ src, const int* __restrict__ dst, float* __restrict__ agg)
{
  constexpr int KS   = (HIDK * MIP) / 32;          // multiple of 4
  constexpr int NF   = MO / 16;                    // total col fragments
  constexpr int NFW  = NF / 2;                     // col fragments per wave
  constexpr int NBLK = MIP / 8;                    // 16B blocks per hs row
  constexpr int HIDP = (MIP == 8) ? 148 : ((HIDK + 3) & ~3);
  static_assert((KS & 3) == 0, "KS must be multiple of 4");

  __shared__ __align__(8)  _Float16 hid_lds[128][HIDP];
  __shared__ __align__(16) _Float16 hs_lds[128][MIP];   // XOR-swizzled 16B blocks
  __shared__ float ea_lds[128][5];
  __shared__ float w1_lds[5][128];
  __shared__ float b1_lds[128];
  __shared__ int   src_l[128];
  __shared__ int   dst_l[128];

  const int tid  = threadIdx.x;
  const int lane = tid & 63;
  const int wave = tid >> 6;
  const int eh   = wave >> 1;          // edge half (0/1)
  const int nh   = wave & 1;           // col half (0/1)
  const int c15  = lane & 15;
  const int g    = lane >> 4;
  const int e0   = blockIdx.x * 128;
  const int nf0  = nh * NFW;

  // phase 0: stage small stuff
  for (int t = tid; t < 640; t += 256) w1_lds[t >> 7][t & 127] = w1[t];
  if (tid < 128) b1_lds[tid] = b1[tid];
  for (int t = tid; t < 640; t += 256) ea_lds[t / 5][t % 5] = ea[(size_t)e0 * 5 + t];
  if (tid < 128){ src_l[tid] = src[e0 + tid]; dst_l[tid] = dst[e0 + tid]; }
  __syncthreads();

  // phase 1: hid = relu(ea@w1+b1) (f16); row 128 = 1 (bias), rows >128 = 0.
  for (int t = tid; t < 128 * HIDK; t += 256){
    int e = t / HIDK, k = t - e * HIDK;
    float s;
    if (k < 128){
      s = b1_lds[k];
      #pragma unroll
      for (int j = 0; j < 5; ++j) s += ea_lds[e][j] * w1_lds[j][k];
      s = fmaxf(s, 0.f);
    } else s = (k == 128) ? 1.f : 0.f;
    hid_lds[e][k] = (_Float16)s;
  }
  // gather h_src (f16, zero-pad i>=MIR), block-swizzled
  for (int t = tid; t < 128 * MIP; t += 256){
    int e = t / MIP, i = t - e * MIP;
    int bw = ((i >> 3) ^ (e & (NBLK - 1)));
    hs_lds[e][(bw << 3) | (i & 7)] =
        (i < MIR) ? (_Float16)h[(size_t)src_l[e] * MIR + i] : (_Float16)0.f;
  }
  __syncthreads();

  const f16x8* __restrict__ btv = (const f16x8*)bt;
  f32x4 acc[4][NFW];
  #pragma unroll
  for (int m = 0; m < 4; ++m)
    #pragma unroll
    for (int n = 0; n < NFW; ++n) acc[m][n] = (f32x4){0.f, 0.f, 0.f, 0.f};

  // A hoist: hs fragments live in registers for the whole K loop
  f16x8 hsh[4][2];
  #pragma unroll
  for (int m = 0; m < 4; ++m){
    const int er = eh * 64 + m * 16 + c15;
    if constexpr (MIP == 8){
      hsh[m][0] = *(const f16x8*)&hs_lds[er][0];
      hsh[m][1] = hsh[m][0];
    } else if constexpr (MIP == 32){
      int blk = g ^ (er & 3);
      hsh[m][0] = *(const f16x8*)&hs_lds[er][blk << 3];
      hsh[m][1] = hsh[m][0];
    } else {
      int b0 = g ^ (er & 7), b1x = (4 + g) ^ (er & 7);
      hsh[m][0] = *(const f16x8*)&hs_lds[er][b0 << 3];
      hsh[m][1] = *(const f16x8*)&hs_lds[er][b1x << 3];
    }
  }

  // B prologue: 4 slots = ks 0..3 (this wave's column fragments only)
  f16x8 bq0[NFW], bq1[NFW], bq2[NFW], bq3[NFW];
  #pragma unroll
  for (int n = 0; n < NFW; ++n){
    bq0[n] = btv[(size_t)(0 * NF + nf0 + n) * 64 + lane];
    bq1[n] = btv[(size_t)(1 * NF + nf0 + n) * 64 + lane];
    bq2[n] = btv[(size_t)(2 * NF + nf0 + n) * 64 + lane];
    bq3[n] = btv[(size_t)(3 * NF + nf0 + n) * 64 + lane];
  }

#define EDGE_SUB(U, BQ)                                                          \
  {                                                                              \
    _Pragma("unroll")                                                            \
    for (int m = 0; m < 4; ++m){                                                 \
      _Float16 hv;                                                               \
      f16x8 hs8;                                                                 \
      if constexpr (MIP == 64){ hv = hvp[m][(U) >> 1]; hs8 = hsh[m][(U) & 1]; }  \
      else if constexpr (MIP == 32){ hv = hv4[m][(U)]; hs8 = hsh[m][0]; }        \
      else { hv = hid_lds[eh * 64 + m * 16 + c15][((ks0 + (U)) << 2) + g];       \
             hs8 = hsh[m][0]; }                                                  \
      f16x8 hvv = {hv, hv, hv, hv, hv, hv, hv, hv};                              \
      f16x8 av  = hs8 * hvv;                                                     \
      _Pragma("unroll")                                                          \
      for (int n = 0; n < NFW; ++n)                                              \
        acc[m][n] = __builtin_amdgcn_mfma_f32_16x16x32_f16(av, BQ[n],            \
                                                           acc[m][n], 0, 0, 0); \
    }                                                                            \
    _Pragma("unroll")                                                            \
    for (int n = 0; n < NFW; ++n)                                                \
      BQ[n] = btv[(size_t)((ks0 + (U) + 4) * NF + nf0 + n) * 64 + lane];         \
  }

  for (int ks0 = 0; ks0 < KS; ks0 += 4){
    f16x2 hvp[4]; f16x4 hv4[4];
    if constexpr (MIP == 64){
      #pragma unroll
      for (int m = 0; m < 4; ++m)
        hvp[m] = *(const f16x2*)&hid_lds[eh * 64 + m * 16 + c15][ks0 >> 1];
    } else if constexpr (MIP == 32){
      #pragma unroll
      for (int m = 0; m < 4; ++m)
        hv4[m] = *(const f16x4*)&hid_lds[eh * 64 + m * 16 + c15][ks0];
    }
    (void)hvp; (void)hv4;
    EDGE_SUB(0, bq0)
    EDGE_SUB(1, bq1)
    EDGE_SUB(2, bq2)
    EDGE_SUB(3, bq3)
  }
#undef EDGE_SUB

  // epilogue: C row = (lane>>4)*4+j, col = lane&15
  #pragma unroll
  for (int m = 0; m < 4; ++m)
    #pragma unroll
    for (int n = 0; n < NFW; ++n)
      #pragma unroll
      for (int j = 0; j < 4; ++j){
        int er = eh * 64 + m * 16 + (g << 2) + j;
        atomicAdd(&agg[(size_t)dst_l[er] * MO + (nf0 + n) * 16 + c15], acc[m][n][j]);
      }
}

__global__ void elu_kernel(const float* __restrict__ agg, float* __restrict__ h, int n){
  int i = blockIdx.x * blockDim.x + threadIdx.x;
  if (i < n) h[i] = eluf(agg[i]);
}

__global__ void zero_kernel(float* __restrict__ p, int n){
  int i = blockIdx.x * blockDim.x + threadIdx.x;
  if (i < n) p[i] = 0.f;
}

__global__ void pool_kernel(const float* __restrict__ h, const float* __restrict__ x,
                            const int* __restrict__ batch,
                            float* __restrict__ sums, float* __restrict__ cnts){
  int idx = blockIdx.x * blockDim.x + threadIdx.x;
  if (idx >= Nn * 75) return;
  int n = idx / 75, f = idx - n * 75;
  float v = (f < 64) ? h[(size_t)n * 64 + f] : x[(size_t)n * 16 + 5 + (f - 64)];
  int b = batch[n];
  atomicAdd(&sums[(size_t)b * 75 + f], v);
  if (f == 0) atomicAdd(&cnts[b], 1.f);
}

__global__ __launch_bounds__(64) void head_kernel(
    const float* __restrict__ sums, const float* __restrict__ cnts,
    const float* __restrict__ fc1w, const float* __restrict__ fc1b,
    const float* __restrict__ fc2w, const float* __restrict__ fc2b,
    const float* __restrict__ fc3w, const float* __restrict__ fc3b,
    float* __restrict__ out)
{
  __shared__ float m[64][77];
  __shared__ float a1[64][33];
  __shared__ float a2[64][17];
  int t = threadIdx.x;
  int g = blockIdx.x * 64 + t;
  bool ok = g < Gg;
  float c = ok ? fmaxf(cnts[g], 1.f) : 1.f;
  for (int f = 0; f < 75; ++f) m[t][f] = ok ? sums[(size_t)g * 75 + f] / c : 0.f;
  for (int j = 0; j < 32; ++j){
    float s = fc1b[j];
    for (int f = 0; f < 75; ++f) s += m[t][f] * fc1w[f * 32 + j];
    a1[t][j] = eluf(s);
  }
  for (int j = 0; j < 16; ++j){
    float s = fc2b[j];
    for (int i = 0; i < 32; ++i) s += a1[t][i] * fc2w[i * 16 + j];
    a2[t][j] = eluf(s);
  }
  float s = fc3b[0];
  for (int i = 0; i < 16; ++i) s += a2[t][i] * fc3w[i];
  if (ok) out[g] = s;
}

extern "C" void kernel_launch(void* const* d_in, const int* in_sizes, int n_in,
                              void* d_out, int out_size, void* d_ws, size_t ws_size,
                              hipStream_t stream)
{
  (void)in_sizes; (void)n_in; (void)out_size; (void)ws_size;
  const float* x     = (const float*)d_in[0];
  const int*   ei    = (const int*)d_in[1];
  const float* ea    = (const float*)d_in[2];
  const int*   batch = (const int*)d_in[3];
  const float* cw1[3]   = {(const float*)d_in[4],  (const float*)d_in[10], (const float*)d_in[16]};
  const float* cb1[3]   = {(const float*)d_in[5],  (const float*)d_in[11], (const float*)d_in[17]};
  const float* cw2[3]   = {(const float*)d_in[6],  (const float*)d_in[12], (const float*)d_in[18]};
  const float* cb2[3]   = {(const float*)d_in[7],  (const float*)d_in[13], (const float*)d_in[19]};
  const float* croot[3] = {(const float*)d_in[8],  (const float*)d_in[14], (const float*)d_in[20]};
  const float* cbias[3] = {(const float*)d_in[9],  (const float*)d_in[15], (const float*)d_in[21]};
  const float* fc1w = (const float*)d_in[22];
  const float* fc1b = (const float*)d_in[23];
  const float* fc2w = (const float*)d_in[24];
  const float* fc2b = (const float*)d_in[25];
  const float* fc3w = (const float*)d_in[26];
  const float* fc3b = (const float*)d_in[27];
  float* out = (float*)d_out;

  float* ws   = (float*)d_ws;
  float* h    = ws;                              // N*64
  float* agg  = h + (size_t)Nn * 64;             // N*64
  float* sums = agg + (size_t)Nn * 64;           // G*75
  float* cnts = sums + (size_t)Gg * 75;          // G
  // bt arrays sized with +4 ks-slots of prefetch headroom
  _Float16* bt1 = (_Float16*)(cnts + Gg);        // 2*(36+4)*512  = 40960
  _Float16* bt2 = bt1 + 40960;                   // 4*(132+4)*512 = 278528
  _Float16* bt3 = bt2 + 278528;                  // 4*(260+4)*512 = 540672

  const int* src = ei;
  const int* dst = ei + Ee;

  h0_kernel<<<(Nn * 5 + 255) / 256, 256, 0, stream>>>(x, h);
  bt_kernel<5, 8, 32, 144><<<(2 * 36 * 512 + 255) / 256, 256, 0, stream>>>(cw2[0], cb2[0], bt1);
  bt_kernel<32, 32, 64, 132><<<(4 * 132 * 512 + 255) / 256, 256, 0, stream>>>(cw2[1], cb2[1], bt2);
  bt_kernel<64, 64, 64, 130><<<(4 * 260 * 512 + 255) / 256, 256, 0, stream>>>(cw2[2], cb2[2], bt3);

  // ---- layer 1: MI=5 (pad 8), MO=32 ----
  node_kernel<5, 32><<<(Nn * 32 + 255) / 256, 256, 0, stream>>>(h, croot[0], cbias[0], agg);
  edge_mfma<5, 8, 32, 144><<<Ee / 128, 256, 0, stream>>>(ea, cw1[0], cb1[0], bt1, h, src, dst, agg);
  elu_kernel<<<(Nn * 32 + 255) / 256, 256, 0, stream>>>(agg, h, Nn * 32);

  // ---- layer 2: MI=32, MO=64 ----
  node_kernel<32, 64><<<(Nn * 64 + 255) / 256, 256, 0, stream>>>(h, croot[1], cbias[1], agg);
  edge_mfma<32, 32, 64, 132><<<Ee / 128, 256, 0, stream>>>(ea, cw1[1], cb1[1], bt2, h, src, dst, agg);
  elu_kernel<<<(Nn * 64 + 255) / 256, 256, 0, stream>>>(agg, h, Nn * 64);

  // ---- layer 3: MI=64, MO=64 ----
  node_kernel<64, 64><<<(Nn * 64 + 255) / 256, 256, 0, stream>>>(h, croot[2], cbias[2], agg);
  edge_mfma<64, 64, 64, 130><<<Ee / 128, 256, 0, stream>>>(ea, cw1[2], cb1[2], bt3, h, src, dst, agg);
  elu_kernel<<<(Nn * 64 + 255) / 256, 256, 0, stream>>>(agg, h, Nn * 64);

  // ---- pooling + head ----
  zero_kernel<<<(Gg * 76 + 255) / 256, 256, 0, stream>>>(sums, Gg * 76);
  pool_kernel<<<(Nn * 75 + 255) / 256, 256, 0, stream>>>(h, x, batch, sums, cnts);
  head_kernel<<<(Gg + 63) / 64, 64, 0, stream>>>(sums, cnts, fc1w, fc1b, fc2w, fc2b, fc3w, fc3b, out);
}

// Round 6
// 322.132 us; speedup vs baseline: 1.2180x; 1.2180x over previous
//
#include <hip/hip_runtime.h>
#include <math.h>

#define HID 128
constexpr int Nn = 20000;
constexpr int Ee = 80000;
constexpr int Gg = 1000;

typedef _Float16 f16x8 __attribute__((ext_vector_type(8)));
typedef _Float16 f16x4 __attribute__((ext_vector_type(4)));
typedef _Float16 f16x2 __attribute__((ext_vector_type(2)));
typedef float    f32x4 __attribute__((ext_vector_type(4)));

__device__ __forceinline__ float eluf(float x){ return x > 0.f ? x : (expf(x) - 1.f); }

// h0 = x[:, :5]
__global__ void h0_kernel(const float* __restrict__ x, float* __restrict__ h){
  int idx = blockIdx.x * blockDim.x + threadIdx.x;
  if (idx >= Nn * 5) return;
  int n = idx / 5, c = idx - n * 5;
  h[idx] = x[(size_t)n * 16 + c];
}

// ---- B permute for MFMA edge GEMM (ks-major layout) ----
// bt[((ks*NF + n)*64 + l)*8 + j] = B[ks*32 + (l>>4)*8 + j][n*16 + (l&15)]
template<int MIR, int MIP, int MO, int HIDK>
__global__ void bt_kernel(const float* __restrict__ w2, const float* __restrict__ b2,
                          _Float16* __restrict__ bt){
  constexpr int KS = (HIDK * MIP) / 32;
  constexpr int NF = MO / 16;
  int idx = blockIdx.x * 256 + threadIdx.x;
  if (idx >= NF * KS * 512) return;
  int j  = idx & 7;
  int l  = (idx >> 3) & 63;
  int n  = (idx >> 9) % NF;
  int ks = idx / (NF * 512);
  int col = n * 16 + (l & 15);
  int kk  = ks * 32 + ((l >> 4) << 3) + j;
  int k = kk / MIP, i = kk % MIP;
  float v = 0.f;
  if (i < MIR){
    if (k < 128)       v = w2[(size_t)k * (MIR * MO) + i * MO + col];
    else if (k == 128) v = b2[i * MO + col];
  }
  bt[idx] = (_Float16)v;
}

// agg[n,o] = bias[o] + sum_i h[n,i]*root[i,o]
template<int MI, int MO>
__global__ void node_kernel(const float* __restrict__ h, const float* __restrict__ root,
                            const float* __restrict__ bias, float* __restrict__ agg){
  int idx = blockIdx.x * blockDim.x + threadIdx.x;
  if (idx >= Nn * MO) return;
  int n = idx / MO, o = idx - n * MO;
  float s = bias[o];
  #pragma unroll
  for (int i = 0; i < MI; ++i) s += h[(size_t)n * MI + i] * root[i * MO + o];
  agg[idx] = s;
}

// ---- MFMA edge kernel: 4 waves/WG, 128 edges/WG, K-sliced via blockIdx.y ----
// wave = (edge-half, col-half): 64 edges x MO/2 cols per wave.
// depth-4 B prefetch, A hoisted to registers, swizzled hs_lds.
template<int MIR, int MIP, int MO, int HIDK>
__global__ __launch_bounds__(256) void edge_mfma(
    const float* __restrict__ ea, const float* __restrict__ w1, const float* __restrict__ b1,
    const _Float16* __restrict__ bt, const float* __restrict__ h,
    const int* __restrict__ src, const int* __restrict__ dst, float* __restrict__ agg)
{
  constexpr int NF   = MO / 16;                    // total col fragments
  constexpr int NFW  = NF / 2;                     // col fragments per wave
  constexpr int NBLK = MIP / 8;                    // 16B blocks per hs row
  constexpr int KHC  = (MIP == 8) ? 144 : 68;      // hid rows per slice (padded)
  constexpr int HIDP = (MIP == 8) ? 148 : 68;

  // per-slice K windows (k-aligned; kk = k*MIP + i)
  const int slice = blockIdx.y;
  int KS0, KSN, K0, KH;
  if constexpr (MIP == 64){        // HIDK=130, KS=260
    KS0 = slice ? 132 : 0;  KSN = slice ? 128 : 132;
    K0  = slice ? 66  : 0;  KH  = slice ? 65  : 66;
  } else if constexpr (MIP == 32){ // HIDK=132, KS=132
    KS0 = slice ? 68 : 0;   KSN = slice ? 64 : 68;
    K0  = slice ? 68 : 0;   KH  = slice ? 64 : 68;
  } else {                         // MIP=8, HIDK=144, KS=36, single slice
    KS0 = 0; KSN = 36; K0 = 0; KH = 144;
  }

  __shared__ __align__(8)  _Float16 hid_lds[128][HIDP];
  __shared__ __align__(16) _Float16 hs_lds[128][MIP];   // XOR-swizzled 16B blocks
  __shared__ float ea_lds[128][5];
  __shared__ int   src_l[128];
  __shared__ int   dst_l[128];

  const int tid  = threadIdx.x;
  const int lane = tid & 63;
  const int wave = tid >> 6;
  const int eh   = wave >> 1;          // edge half (0/1)
  const int nh   = wave & 1;           // col half (0/1)
  const int c15  = lane & 15;
  const int g    = lane >> 4;
  const int e0   = blockIdx.x * 128;
  const int nf0  = nh * NFW;

  // phase 0: stage tile data
  for (int t = tid; t < 640; t += 256) ea_lds[t / 5][t % 5] = ea[(size_t)e0 * 5 + t];
  if (tid < 128){ src_l[tid] = src[e0 + tid]; dst_l[tid] = dst[e0 + tid]; }
  __syncthreads();

  // phase 1: hid rows [K0, K0+KH) = relu(ea@w1+b1) (f16); global row 128 = 1, >128 = 0.
  for (int t = tid; t < 128 * KHC; t += 256){
    int e = t / KHC, k = t - e * KHC;
    if (k < KH){
      int gk = K0 + k;
      float s;
      if (gk < 128){
        s = b1[gk];
        #pragma unroll
        for (int j = 0; j < 5; ++j) s += ea_lds[e][j] * w1[j * 128 + gk];
        s = fmaxf(s, 0.f);
      } else s = (gk == 128) ? 1.f : 0.f;
      hid_lds[e][k] = (_Float16)s;
    }
  }
  // gather h_src (f16, zero-pad i>=MIR), block-swizzled
  for (int t = tid; t < 128 * MIP; t += 256){
    int e = t / MIP, i = t - e * MIP;
    int bw = ((i >> 3) ^ (e & (NBLK - 1)));
    hs_lds[e][(bw << 3) | (i & 7)] =
        (i < MIR) ? (_Float16)h[(size_t)src_l[e] * MIR + i] : (_Float16)0.f;
  }
  __syncthreads();

  // slice-local B base
  const f16x8* __restrict__ btv = ((const f16x8*)bt) + (size_t)KS0 * NF * 64;
  const int kofs  = (KS0 >> 1) - K0;   // == 0 by slice construction (MIP=64)
  const int kofs32 = KS0 - K0;         // == 0 by slice construction (MIP=32)

  f32x4 acc[4][NFW];
  #pragma unroll
  for (int m = 0; m < 4; ++m)
    #pragma unroll
    for (int n = 0; n < NFW; ++n) acc[m][n] = (f32x4){0.f, 0.f, 0.f, 0.f};

  // A hoist: hs fragments live in registers for the whole K loop
  f16x8 hsh[4][2];
  #pragma unroll
  for (int m = 0; m < 4; ++m){
    const int er = eh * 64 + m * 16 + c15;
    if constexpr (MIP == 8){
      hsh[m][0] = *(const f16x8*)&hs_lds[er][0];
      hsh[m][1] = hsh[m][0];
    } else if constexpr (MIP == 32){
      int blk = g ^ (er & 3);
      hsh[m][0] = *(const f16x8*)&hs_lds[er][blk << 3];
      hsh[m][1] = hsh[m][0];
    } else {
      int b0 = g ^ (er & 7), b1x = (4 + g) ^ (er & 7);
      hsh[m][0] = *(const f16x8*)&hs_lds[er][b0 << 3];
      hsh[m][1] = *(const f16x8*)&hs_lds[er][b1x << 3];
    }
  }

  // B prologue: 4 slots = slice-local ks 0..3 (this wave's column fragments only)
  f16x8 bq0[NFW], bq1[NFW], bq2[NFW], bq3[NFW];
  #pragma unroll
  for (int n = 0; n < NFW; ++n){
    bq0[n] = btv[(size_t)(0 * NF + nf0 + n) * 64 + lane];
    bq1[n] = btv[(size_t)(1 * NF + nf0 + n) * 64 + lane];
    bq2[n] = btv[(size_t)(2 * NF + nf0 + n) * 64 + lane];
    bq3[n] = btv[(size_t)(3 * NF + nf0 + n) * 64 + lane];
  }

#define EDGE_SUB(U, BQ)                                                          \
  {                                                                              \
    _Pragma("unroll")                                                            \
    for (int m = 0; m < 4; ++m){                                                 \
      _Float16 hv;                                                               \
      f16x8 hs8;                                                                 \
      if constexpr (MIP == 64){ hv = hvp[m][(U) >> 1]; hs8 = hsh[m][(U) & 1]; }  \
      else if constexpr (MIP == 32){ hv = hv4[m][(U)]; hs8 = hsh[m][0]; }        \
      else { hv = hid_lds[eh * 64 + m * 16 + c15][((ks0 + (U)) << 2) + g];       \
             hs8 = hsh[m][0]; }                                                  \
      f16x8 hvv = {hv, hv, hv, hv, hv, hv, hv, hv};                              \
      f16x8 av  = hs8 * hvv;                                                     \
      _Pragma("unroll")                                                          \
      for (int n = 0; n < NFW; ++n)                                              \
        acc[m][n] = __builtin_amdgcn_mfma_f32_16x16x32_f16(av, BQ[n],            \
                                                           acc[m][n], 0, 0, 0); \
    }                                                                            \
    _Pragma("unroll")                                                            \
    for (int n = 0; n < NFW; ++n)                                                \
      BQ[n] = btv[(size_t)((ks0 + (U) + 4) * NF + nf0 + n) * 64 + lane];         \
  }

  for (int ks0 = 0; ks0 < KSN; ks0 += 4){
    f16x2 hvp[4]; f16x4 hv4[4];
    if constexpr (MIP == 64){
      #pragma unroll
      for (int m = 0; m < 4; ++m)
        hvp[m] = *(const f16x2*)&hid_lds[eh * 64 + m * 16 + c15][(ks0 >> 1) + kofs];
    } else if constexpr (MIP == 32){
      #pragma unroll
      for (int m = 0; m < 4; ++m)
        hv4[m] = *(const f16x4*)&hid_lds[eh * 64 + m * 16 + c15][ks0 + kofs32];
    }
    (void)hvp; (void)hv4;
    EDGE_SUB(0, bq0)
    EDGE_SUB(1, bq1)
    EDGE_SUB(2, bq2)
    EDGE_SUB(3, bq3)
  }
#undef EDGE_SUB

  // epilogue: C row = (lane>>4)*4+j, col = lane&15
  #pragma unroll
  for (int m = 0; m < 4; ++m)
    #pragma unroll
    for (int n = 0; n < NFW; ++n)
      #pragma unroll
      for (int j = 0; j < 4; ++j){
        int er = eh * 64 + m * 16 + (g << 2) + j;
        atomicAdd(&agg[(size_t)dst_l[er] * MO + (nf0 + n) * 16 + c15], acc[m][n][j]);
      }
}

__global__ void elu_kernel(const float* __restrict__ agg, float* __restrict__ h, int n){
  int i = blockIdx.x * blockDim.x + threadIdx.x;
  if (i < n) h[i] = eluf(agg[i]);
}

__global__ void zero_kernel(float* __restrict__ p, int n){
  int i = blockIdx.x * blockDim.x + threadIdx.x;
  if (i < n) p[i] = 0.f;
}

__global__ void pool_kernel(const float* __restrict__ h, const float* __restrict__ x,
                            const int* __restrict__ batch,
                            float* __restrict__ sums, float* __restrict__ cnts){
  int idx = blockIdx.x * blockDim.x + threadIdx.x;
  if (idx >= Nn * 75) return;
  int n = idx / 75, f = idx - n * 75;
  float v = (f < 64) ? h[(size_t)n * 64 + f] : x[(size_t)n * 16 + 5 + (f - 64)];
  int b = batch[n];
  atomicAdd(&sums[(size_t)b * 75 + f], v);
  if (f == 0) atomicAdd(&cnts[b], 1.f);
}

__global__ __launch_bounds__(64) void head_kernel(
    const float* __restrict__ sums, const float* __restrict__ cnts,
    const float* __restrict__ fc1w, const float* __restrict__ fc1b,
    const float* __restrict__ fc2w, const float* __restrict__ fc2b,
    const float* __restrict__ fc3w, const float* __restrict__ fc3b,
    float* __restrict__ out)
{
  __shared__ float m[64][77];
  __shared__ float a1[64][33];
  __shared__ float a2[64][17];
  int t = threadIdx.x;
  int g = blockIdx.x * 64 + t;
  bool ok = g < Gg;
  float c = ok ? fmaxf(cnts[g], 1.f) : 1.f;
  for (int f = 0; f < 75; ++f) m[t][f] = ok ? sums[(size_t)g * 75 + f] / c : 0.f;
  for (int j = 0; j < 32; ++j){
    float s = fc1b[j];
    for (int f = 0; f < 75; ++f) s += m[t][f] * fc1w[f * 32 + j];
    a1[t][j] = eluf(s);
  }
  for (int j = 0; j < 16; ++j){
    float s = fc2b[j];
    for (int i = 0; i < 32; ++i) s += a1[t][i] * fc2w[i * 16 + j];
    a2[t][j] = eluf(s);
  }
  float s = fc3b[0];
  for (int i = 0; i < 16; ++i) s += a2[t][i] * fc3w[i];
  if (ok) out[g] = s;
}

extern "C" void kernel_launch(void* const* d_in, const int* in_sizes, int n_in,
                              void* d_out, int out_size, void* d_ws, size_t ws_size,
                              hipStream_t stream)
{
  (void)in_sizes; (void)n_in; (void)out_size; (void)ws_size;
  const float* x     = (const float*)d_in[0];
  const int*   ei    = (const int*)d_in[1];
  const float* ea    = (const float*)d_in[2];
  const int*   batch = (const int*)d_in[3];
  const float* cw1[3]   = {(const float*)d_in[4],  (const float*)d_in[10], (const float*)d_in[16]};
  const float* cb1[3]   = {(const float*)d_in[5],  (const float*)d_in[11], (const float*)d_in[17]};
  const float* cw2[3]   = {(const float*)d_in[6],  (const float*)d_in[12], (const float*)d_in[18]};
  const float* cb2[3]   = {(const float*)d_in[7],  (const float*)d_in[13], (const float*)d_in[19]};
  const float* croot[3] = {(const float*)d_in[8],  (const float*)d_in[14], (const float*)d_in[20]};
  const float* cbias[3] = {(const float*)d_in[9],  (const float*)d_in[15], (const float*)d_in[21]};
  const float* fc1w = (const float*)d_in[22];
  const float* fc1b = (const float*)d_in[23];
  const float* fc2w = (const float*)d_in[24];
  const float* fc2b = (const float*)d_in[25];
  const float* fc3w = (const float*)d_in[26];
  const float* fc3b = (const float*)d_in[27];
  float* out = (float*)d_out;

  float* ws   = (float*)d_ws;
  float* h    = ws;                              // N*64
  float* agg  = h + (size_t)Nn * 64;             // N*64
  float* sums = agg + (size_t)Nn * 64;           // G*75
  float* cnts = sums + (size_t)Gg * 75;          // G
  // bt arrays sized with +4 ks-slots of prefetch headroom
  _Float16* bt1 = (_Float16*)(cnts + Gg);        // 2*(36+4)*512  = 40960
  _Float16* bt2 = bt1 + 40960;                   // 4*(132+4)*512 = 278528
  _Float16* bt3 = bt2 + 278528;                  // 4*(260+4)*512 = 540672

  const int* src = ei;
  const int* dst = ei + Ee;

  h0_kernel<<<(Nn * 5 + 255) / 256, 256, 0, stream>>>(x, h);
  bt_kernel<5, 8, 32, 144><<<(2 * 36 * 512 + 255) / 256, 256, 0, stream>>>(cw2[0], cb2[0], bt1);
  bt_kernel<32, 32, 64, 132><<<(4 * 132 * 512 + 255) / 256, 256, 0, stream>>>(cw2[1], cb2[1], bt2);
  bt_kernel<64, 64, 64, 130><<<(4 * 260 * 512 + 255) / 256, 256, 0, stream>>>(cw2[2], cb2[2], bt3);

  // ---- layer 1: MI=5 (pad 8), MO=32, single K slice ----
  node_kernel<5, 32><<<(Nn * 32 + 255) / 256, 256, 0, stream>>>(h, croot[0], cbias[0], agg);
  edge_mfma<5, 8, 32, 144><<<dim3(Ee / 128, 1), 256, 0, stream>>>(ea, cw1[0], cb1[0], bt1, h, src, dst, agg);
  elu_kernel<<<(Nn * 32 + 255) / 256, 256, 0, stream>>>(agg, h, Nn * 32);

  // ---- layer 2: MI=32, MO=64, 2 K slices ----
  node_kernel<32, 64><<<(Nn * 64 + 255) / 256, 256, 0, stream>>>(h, croot[1], cbias[1], agg);
  edge_mfma<32, 32, 64, 132><<<dim3(Ee / 128, 2), 256, 0, stream>>>(ea, cw1[1], cb1[1], bt2, h, src, dst, agg);
  elu_kernel<<<(Nn * 64 + 255) / 256, 256, 0, stream>>>(agg, h, Nn * 64);

  // ---- layer 3: MI=64, MO=64, 2 K slices ----
  node_kernel<64, 64><<<(Nn * 64 + 255) / 256, 256, 0, stream>>>(h, croot[2], cbias[2], agg);
  edge_mfma<64, 64, 64, 130><<<dim3(Ee / 128, 2), 256, 0, stream>>>(ea, cw1[2], cb1[2], bt3, h, src, dst, agg);
  elu_kernel<<<(Nn * 64 + 255) / 256, 256, 0, stream>>>(agg, h, Nn * 64);

  // ---- pooling + head ----
  zero_kernel<<<(Gg * 76 + 255) / 256, 256, 0, stream>>>(sums, Gg * 76);
  pool_kernel<<<(Nn * 75 + 255) / 256, 256, 0, stream>>>(h, x, batch, sums, cnts);
  head_kernel<<<(Gg + 63) / 64, 64, 0, stream>>>(sums, cnts, fc1w, fc1b, fc2w, fc2b, fc3w, fc3b, out);
}

// Round 8
// 306.940 us; speedup vs baseline: 1.2783x; 1.0495x over previous
//
#include <hip/hip_runtime.h>
#include <math.h>

constexpr int Nn = 20000;
constexpr int Ee = 80000;
constexpr int Gg = 1000;

typedef _Float16 f16x8 __attribute__((ext_vector_type(8)));
typedef _Float16 f16x2 __attribute__((ext_vector_type(2)));
typedef float    f32x4 __attribute__((ext_vector_type(4)));

__device__ __forceinline__ float eluf(float x){ return x > 0.f ? x : (expf(x) - 1.f); }

// ---- fused B permute for all 3 layers (ks-major fragment layout) ----
// bt[((ks*NF + n)*64 + l)*8 + j] = B[ks*32 + (l>>4)*8 + j][n*16 + (l&15)]
__device__ __forceinline__ void bt_emit(int idx, int lgNF, int MIR, int s, int MO,
                                        const float* __restrict__ w2,
                                        const float* __restrict__ b2,
                                        _Float16* __restrict__ bt){
  int NF = 1 << lgNF;
  int j  = idx & 7;
  int l  = (idx >> 3) & 63;
  int n  = (idx >> 9) & (NF - 1);
  int ks = idx >> (9 + lgNF);
  int col = n * 16 + (l & 15);
  int kk  = ks * 32 + ((l >> 4) << 3) + j;
  int k = kk >> s, i = kk & ((1 << s) - 1);
  float v = 0.f;
  if (i < MIR){
    if (k < 128)       v = w2[(size_t)k * (MIR * MO) + i * MO + col];
    else if (k == 128) v = b2[i * MO + col];
  }
  bt[idx] = (_Float16)v;
}

__global__ void bt_all(const float* __restrict__ w21, const float* __restrict__ b21,
                       const float* __restrict__ w22, const float* __restrict__ b22,
                       const float* __restrict__ w23, const float* __restrict__ b23,
                       _Float16* __restrict__ bt1, _Float16* __restrict__ bt2,
                       _Float16* __restrict__ bt3){
  int idx = blockIdx.x * 256 + threadIdx.x;
  if (idx < 36864)                 bt_emit(idx,                1, 5,  3, 32, w21, b21, bt1);
  else if (idx < 36864 + 270336)   bt_emit(idx - 36864,        2, 32, 5, 64, w22, b22, bt2);
  else if (idx < 839680)           bt_emit(idx - 307200,       2, 64, 6, 64, w23, b23, bt3);
}

// agg[n,o] = bias[o] + sum_i h[n,i]*root[i,o]   (h has row stride ldh)
template<int MI, int MO>
__global__ void node_kernel(const float* __restrict__ h, int ldh,
                            const float* __restrict__ root,
                            const float* __restrict__ bias, float* __restrict__ agg){
  int idx = blockIdx.x * blockDim.x + threadIdx.x;
  if (idx >= Nn * MO) return;
  int n = idx / MO, o = idx - n * MO;
  float s = bias[o];
  #pragma unroll
  for (int i = 0; i < MI; ++i) s += h[(size_t)n * ldh + i] * root[i * MO + o];
  agg[idx] = s;
}

// h_out = elu(agg_prev); agg_next = bias + h_out @ root
template<int MI, int MO>
__global__ __launch_bounds__(256) void elu_node_kernel(
    const float* __restrict__ agg_prev, const float* __restrict__ root,
    const float* __restrict__ bias, float* __restrict__ hout, float* __restrict__ agg_next){
  __shared__ float hl[32][MI + 1];
  int n0 = blockIdx.x * 32;
  int t  = threadIdx.x;
  for (int idx = t; idx < 32 * MI; idx += 256){
    int nl = idx / MI, i = idx - nl * MI;
    float v = eluf(agg_prev[(size_t)(n0 + nl) * MI + i]);
    hl[nl][i] = v;
    hout[(size_t)(n0 + nl) * MI + i] = v;
  }
  __syncthreads();
  for (int idx = t; idx < 32 * MO; idx += 256){
    int nl = idx / MO, o = idx - nl * MO;
    float s = bias[o];
    #pragma unroll 8
    for (int i = 0; i < MI; ++i) s += hl[nl][i] * root[i * MO + o];
    agg_next[(size_t)(n0 + nl) * MO + o] = s;
  }
}

// ---- MFMA edge kernel: 4 waves/WG = (edge-half x K-half), 128 edges/WG,
// grid.y = K slices. Each wave: 64 edges x MO cols x quarter-K.
// av shared across all NF col fragments; K-half partials combined via LDS.
template<int MIR, int MIP, int MO, int HIDK>
__global__ __launch_bounds__(256, 3) void edge_mfma(
    const float* __restrict__ ea, const float* __restrict__ w1, const float* __restrict__ b1,
    const _Float16* __restrict__ bt, const float* __restrict__ h, int ldh,
    const int* __restrict__ src, const int* __restrict__ dst, float* __restrict__ agg)
{
  constexpr int NF   = MO / 16;
  constexpr int NBLK = MIP / 8;
  constexpr int KHC  = (MIP == 8) ? 144 : 68;
  constexpr int HIDP = (MIP == 8) ? 148 : 68;
  constexpr int HID_B  = 128 * HIDP * 2;
  constexpr int HS_B   = 128 * MIP * 2;
  constexpr int COMB_B = 2 * 4 * NF * 64 * 16;     // combine overlay bytes
  constexpr int EA_O   = HID_B + HS_B;
  constexpr int SRC_O  = EA_O + 2560;
  constexpr int STG_E  = SRC_O + 512;              // end of staging layout
  constexpr int DST_O  = (STG_E > COMB_B) ? STG_E : COMB_B;  // dst_l beyond both

  __shared__ __align__(16) char pool[DST_O + 512];
  _Float16* hidp = (_Float16*)pool;
  _Float16* hsp  = (_Float16*)(pool + HID_B);
  float*    eap  = (float*)(pool + EA_O);
  int*      src_l = (int*)(pool + SRC_O);
  int*      dst_l = (int*)(pool + DST_O);

  // per-slice K windows (k-aligned; kk = k*MIP + i)
  const int slice = blockIdx.y;
  int KS0, KSN, K0, KH;
  if constexpr (MIP == 64){        // HIDK=130, KS=260
    KS0 = slice ? 132 : 0;  KSN = slice ? 128 : 132;
    K0  = slice ? 66  : 0;  KH  = slice ? 65  : 66;
  } else if constexpr (MIP == 32){ // HIDK=132, KS=132
    KS0 = slice ? 68 : 0;   KSN = slice ? 64 : 68;
    K0  = slice ? 68 : 0;   KH  = slice ? 64 : 68;
  } else {                         // MIP=8, HIDK=144, KS=36
    KS0 = 0; KSN = 36; K0 = 0; KH = 144;
  }
  const int KSW0 = (KSN / 2 + 3) & ~3;

  const int tid  = threadIdx.x;
  const int lane = tid & 63;
  const int wave = tid >> 6;
  const int eh   = wave & 1;           // edge half
  const int kh   = wave >> 1;          // K half
  const int c15  = lane & 15;
  const int g    = lane >> 4;
  const int e0   = blockIdx.x * 128;
  const int ksb  = kh ? KSW0 : 0;
  const int KSW  = kh ? (KSN - KSW0) : KSW0;

  // phase 0: stage tile data
  for (int t = tid; t < 640; t += 256) eap[t] = ea[(size_t)e0 * 5 + t];
  if (tid < 128){ src_l[tid] = src[e0 + tid]; dst_l[tid] = dst[e0 + tid]; }
  __syncthreads();

  // phase 1: hid rows [K0, K0+KH) = relu(ea@w1+b1); global row 128 = 1, >128 = 0
  for (int t = tid; t < 128 * KHC; t += 256){
    int e = t / KHC, k = t - e * KHC;
    if (k < KH){
      int gk = K0 + k;
      float s;
      if (gk < 128){
        s = b1[gk];
        #pragma unroll
        for (int j = 0; j < 5; ++j) s += eap[e * 5 + j] * w1[j * 128 + gk];
        s = fmaxf(s, 0.f);
      } else s = (gk == 128) ? 1.f : 0.f;
      hidp[e * HIDP + k] = (_Float16)s;
    }
  }
  // gather h_src (f16, zero-pad i>=MIR), block-swizzled
  for (int t = tid; t < 128 * MIP; t += 256){
    int e = t / MIP, i = t - e * MIP;
    int bw = ((i >> 3) ^ (e & (NBLK - 1)));
    hsp[e * MIP + ((bw << 3) | (i & 7))] =
        (i < MIR) ? (_Float16)h[(size_t)src_l[e] * ldh + i] : (_Float16)0.f;
  }
  __syncthreads();

  const f16x8* __restrict__ btv = (const f16x8*)bt;
  int er_[4];
  #pragma unroll
  for (int m = 0; m < 4; ++m) er_[m] = eh * 64 + m * 16 + c15;

  f32x4 acc[4][NF];
  #pragma unroll
  for (int m = 0; m < 4; ++m)
    #pragma unroll
    for (int n = 0; n < NF; ++n) acc[m][n] = (f32x4){0.f, 0.f, 0.f, 0.f};

  // A hoist
  f16x8 hsh[4][2];
  #pragma unroll
  for (int m = 0; m < 4; ++m){
    const int er = er_[m];
    if constexpr (MIP == 8){
      hsh[m][0] = *(const f16x8*)&hsp[er * MIP];
      hsh[m][1] = hsh[m][0];
    } else if constexpr (MIP == 32){
      int blk = g ^ (er & 3);
      hsh[m][0] = *(const f16x8*)&hsp[er * MIP + (blk << 3)];
      hsh[m][1] = hsh[m][0];
    } else {
      int b0 = g ^ (er & 7), b1x = (4 + g) ^ (er & 7);
      hsh[m][0] = *(const f16x8*)&hsp[er * MIP + (b0 << 3)];
      hsh[m][1] = *(const f16x8*)&hsp[er * MIP + (b1x << 3)];
    }
  }

  // B prologue: depth-2 ping-pong
  f16x8 bqA[NF], bqB[NF];
  #pragma unroll
  for (int n = 0; n < NF; ++n){
    bqA[n] = btv[((size_t)(KS0 + ksb + 0) * NF + n) * 64 + lane];
    bqB[n] = btv[((size_t)(KS0 + ksb + 1) * NF + n) * 64 + lane];
  }

#define EDGE_SUB(U, BQ)                                                         \
  {                                                                             \
    _Pragma("unroll")                                                           \
    for (int m = 0; m < 4; ++m){                                                \
      _Float16 hv;                                                              \
      f16x8 hs8;                                                                \
      if constexpr (MIP == 64){ hv = hvS[m]; hs8 = hsh[m][(U)]; }               \
      else if constexpr (MIP == 32){ hv = hv2[m][(U)]; hs8 = hsh[m][0]; }       \
      else { hv = hidp[er_[m] * HIDP + ((ksb + u + (U)) << 2) + g];             \
             hs8 = hsh[m][0]; }                                                 \
      f16x8 hvv = {hv, hv, hv, hv, hv, hv, hv, hv};                             \
      f16x8 av  = hs8 * hvv;                                                    \
      _Pragma("unroll")                                                         \
      for (int n = 0; n < NF; ++n)                                              \
        acc[m][n] = __builtin_amdgcn_mfma_f32_16x16x32_f16(av, BQ[n],           \
                                                           acc[m][n], 0, 0, 0);\
    }                                                                           \
    _Pragma("unroll")                                                           \
    for (int n = 0; n < NF; ++n)                                                \
      BQ[n] = btv[((size_t)(KS0 + ksb + u + (U) + 2) * NF + n) * 64 + lane];    \
  }

  for (int u = 0; u < KSW; u += 2){
    _Float16 hvS[4]; f16x2 hv2[4];
    if constexpr (MIP == 64){
      #pragma unroll
      for (int m = 0; m < 4; ++m) hvS[m] = hidp[er_[m] * HIDP + ((ksb + u) >> 1)];
    } else if constexpr (MIP == 32){
      #pragma unroll
      for (int m = 0; m < 4; ++m) hv2[m] = *(const f16x2*)&hidp[er_[m] * HIDP + (ksb + u)];
    }
    (void)hvS; (void)hv2;
    EDGE_SUB(0, bqA)
    EDGE_SUB(1, bqB)
  }
#undef EDGE_SUB

  // combine K-halves via LDS overlay (hid/hs/ea/src are dead), kh=0 waves do atomics
  __syncthreads();
  float* comb = (float*)pool;
  if (kh == 1){
    #pragma unroll
    for (int m = 0; m < 4; ++m)
      #pragma unroll
      for (int n = 0; n < NF; ++n)
        *(f32x4*)&comb[(((eh * 4 + m) * NF + n) * 64 + lane) * 4] = acc[m][n];
  }
  __syncthreads();
  if (kh == 0){
    #pragma unroll
    for (int m = 0; m < 4; ++m)
      #pragma unroll
      for (int n = 0; n < NF; ++n){
        f32x4 o = *(const f32x4*)&comb[(((eh * 4 + m) * NF + n) * 64 + lane) * 4];
        acc[m][n] += o;
        #pragma unroll
        for (int j = 0; j < 4; ++j){
          int er = eh * 64 + m * 16 + (g << 2) + j;
          atomicAdd(&agg[(size_t)dst_l[er] * MO + n * 16 + c15], acc[m][n][j]);
        }
      }
  }
}

__global__ void zero_kernel(float* __restrict__ p, int n){
  int i = blockIdx.x * blockDim.x + threadIdx.x;
  if (i < n) p[i] = 0.f;
}

// pool with fused elu on the conv output
__global__ void pool_kernel(const float* __restrict__ agg3, const float* __restrict__ x,
                            const int* __restrict__ batch,
                            float* __restrict__ sums, float* __restrict__ cnts){
  int idx = blockIdx.x * blockDim.x + threadIdx.x;
  if (idx >= Nn * 75) return;
  int n = idx / 75, f = idx - n * 75;
  float v = (f < 64) ? eluf(agg3[(size_t)n * 64 + f]) : x[(size_t)n * 16 + 5 + (f - 64)];
  int b = batch[n];
  atomicAdd(&sums[(size_t)b * 75 + f], v);
  if (f == 0) atomicAdd(&cnts[b], 1.f);
}

__global__ __launch_bounds__(64) void head_kernel(
    const float* __restrict__ sums, const float* __restrict__ cnts,
    const float* __restrict__ fc1w, const float* __restrict__ fc1b,
    const float* __restrict__ fc2w, const float* __restrict__ fc2b,
    const float* __restrict__ fc3w, const float* __restrict__ fc3b,
    float* __restrict__ out)
{
  __shared__ float m[64][77];
  __shared__ float a1[64][33];
  __shared__ float a2[64][17];
  int t = threadIdx.x;
  int g = blockIdx.x * 64 + t;
  bool ok = g < Gg;
  float c = ok ? fmaxf(cnts[g], 1.f) : 1.f;
  for (int f = 0; f < 75; ++f) m[t][f] = ok ? sums[(size_t)g * 75 + f] / c : 0.f;
  for (int j = 0; j < 32; ++j){
    float s = fc1b[j];
    for (int f = 0; f < 75; ++f) s += m[t][f] * fc1w[f * 32 + j];
    a1[t][j] = eluf(s);
  }
  for (int j = 0; j < 16; ++j){
    float s = fc2b[j];
    for (int i = 0; i < 32; ++i) s += a1[t][i] * fc2w[i * 16 + j];
    a2[t][j] = eluf(s);
  }
  float s = fc3b[0];
  for (int i = 0; i < 16; ++i) s += a2[t][i] * fc3w[i];
  if (ok) out[g] = s;
}

extern "C" void kernel_launch(void* const* d_in, const int* in_sizes, int n_in,
                              void* d_out, int out_size, void* d_ws, size_t ws_size,
                              hipStream_t stream)
{
  (void)in_sizes; (void)n_in; (void)out_size; (void)ws_size;
  const float* x     = (const float*)d_in[0];
  const int*   ei    = (const int*)d_in[1];
  const float* ea    = (const float*)d_in[2];
  const int*   batch = (const int*)d_in[3];
  const float* cw1[3]   = {(const float*)d_in[4],  (const float*)d_in[10], (const float*)d_in[16]};
  const float* cb1[3]   = {(const float*)d_in[5],  (const float*)d_in[11], (const float*)d_in[17]};
  const float* cw2[3]   = {(const float*)d_in[6],  (const float*)d_in[12], (const float*)d_in[18]};
  const float* cb2[3]   = {(const float*)d_in[7],  (const float*)d_in[13], (const float*)d_in[19]};
  const float* croot[3] = {(const float*)d_in[8],  (const float*)d_in[14], (const float*)d_in[20]};
  const float* cbias[3] = {(const float*)d_in[9],  (const float*)d_in[15], (const float*)d_in[21]};
  const float* fc1w = (const float*)d_in[22];
  const float* fc1b = (const float*)d_in[23];
  const float* fc2w = (const float*)d_in[24];
  const float* fc2b = (const float*)d_in[25];
  const float* fc3w = (const float*)d_in[26];
  const float* fc3b = (const float*)d_in[27];
  float* out = (float*)d_out;

  float* ws   = (float*)d_ws;
  float* h    = ws;                              // N*64
  float* aggA = h + (size_t)Nn * 64;             // N*64
  float* aggB = aggA + (size_t)Nn * 64;          // N*64
  float* sums = aggB + (size_t)Nn * 64;          // G*75
  float* cnts = sums + (size_t)Gg * 75;          // G
  _Float16* bt1 = (_Float16*)(cnts + Gg);        // 2*(36+4)*512  = 40960
  _Float16* bt2 = bt1 + 40960;                   // 4*(132+4)*512 = 278528
  _Float16* bt3 = bt2 + 278528;                  // 4*(260+4)*512 = 540672

  const int* src = ei;
  const int* dst = ei + Ee;

  bt_all<<<3280, 256, 0, stream>>>(cw2[0], cb2[0], cw2[1], cb2[1], cw2[2], cb2[2], bt1, bt2, bt3);

  // ---- layer 1: MI=5 (pad 8), MO=32; h = x (stride 16) ----
  node_kernel<5, 32><<<(Nn * 32 + 255) / 256, 256, 0, stream>>>(x, 16, croot[0], cbias[0], aggA);
  edge_mfma<5, 8, 32, 144><<<dim3(Ee / 128, 1), 256, 0, stream>>>(ea, cw1[0], cb1[0], bt1, x, 16, src, dst, aggA);

  // ---- layer 2: MI=32, MO=64 ----
  elu_node_kernel<32, 64><<<(Nn + 31) / 32, 256, 0, stream>>>(aggA, croot[1], cbias[1], h, aggB);
  edge_mfma<32, 32, 64, 132><<<dim3(Ee / 128, 2), 256, 0, stream>>>(ea, cw1[1], cb1[1], bt2, h, 32, src, dst, aggB);

  // ---- layer 3: MI=64, MO=64 ----
  elu_node_kernel<64, 64><<<(Nn + 31) / 32, 256, 0, stream>>>(aggB, croot[2], cbias[2], h, aggA);
  edge_mfma<64, 64, 64, 130><<<dim3(Ee / 128, 2), 256, 0, stream>>>(ea, cw1[2], cb1[2], bt3, h, 64, src, dst, aggA);

  // ---- pooling (fused elu) + head ----
  zero_kernel<<<(Gg * 76 + 255) / 256, 256, 0, stream>>>(sums, Gg * 76);
  pool_kernel<<<(Nn * 75 + 255) / 256, 256, 0, stream>>>(aggA, x, batch, sums, cnts);
  head_kernel<<<(Gg + 63) / 64, 64, 0, stream>>>(sums, cnts, fc1w, fc1b, fc2w, fc2b, fc3w, fc3b, out);
}

// Round 9
// 265.602 us; speedup vs baseline: 1.4773x; 1.1556x over previous
//
#include <hip/hip_runtime.h>
#include <math.h>

constexpr int Nn = 20000;
constexpr int Ee = 80000;
constexpr int Gg = 1000;

typedef _Float16 f16x8 __attribute__((ext_vector_type(8)));
typedef _Float16 f16x4 __attribute__((ext_vector_type(4)));
typedef _Float16 f16x2 __attribute__((ext_vector_type(2)));
typedef float    f32x4 __attribute__((ext_vector_type(4)));

__device__ __forceinline__ float eluf(float x){ return x > 0.f ? x : (expf(x) - 1.f); }

// ---- fused B permute for all 3 layers (ks-major fragment layout) ----
// bt[((ks*NF + n)*64 + l)*8 + j] = B[ks*32 + (l>>4)*8 + j][n*16 + (l&15)]
__device__ __forceinline__ void bt_emit(int idx, int lgNF, int MIR, int s, int MO,
                                        const float* __restrict__ w2,
                                        const float* __restrict__ b2,
                                        _Float16* __restrict__ bt){
  int NF = 1 << lgNF;
  int j  = idx & 7;
  int l  = (idx >> 3) & 63;
  int n  = (idx >> 9) & (NF - 1);
  int ks = idx >> (9 + lgNF);
  int col = n * 16 + (l & 15);
  int kk  = ks * 32 + ((l >> 4) << 3) + j;
  int k = kk >> s, i = kk & ((1 << s) - 1);
  float v = 0.f;
  if (i < MIR){
    if (k < 128)       v = w2[(size_t)k * (MIR * MO) + i * MO + col];
    else if (k == 128) v = b2[i * MO + col];
  }
  bt[idx] = (_Float16)v;
}

__global__ void bt_all(const float* __restrict__ w21, const float* __restrict__ b21,
                       const float* __restrict__ w22, const float* __restrict__ b22,
                       const float* __restrict__ w23, const float* __restrict__ b23,
                       _Float16* __restrict__ bt1, _Float16* __restrict__ bt2,
                       _Float16* __restrict__ bt3){
  int idx = blockIdx.x * 256 + threadIdx.x;
  if (idx < 36864)                 bt_emit(idx,                1, 5,  3, 32, w21, b21, bt1);
  else if (idx < 36864 + 270336)   bt_emit(idx - 36864,        2, 32, 5, 64, w22, b22, bt2);
  else if (idx < 839680)           bt_emit(idx - 307200,       2, 64, 6, 64, w23, b23, bt3);
}

// agg[n,o] = bias[o] + sum_i h[n,i]*root[i,o]   (h has row stride ldh)
template<int MI, int MO>
__global__ void node_kernel(const float* __restrict__ h, int ldh,
                            const float* __restrict__ root,
                            const float* __restrict__ bias, float* __restrict__ agg){
  int idx = blockIdx.x * blockDim.x + threadIdx.x;
  if (idx >= Nn * MO) return;
  int n = idx / MO, o = idx - n * MO;
  float s = bias[o];
  #pragma unroll
  for (int i = 0; i < MI; ++i) s += h[(size_t)n * ldh + i] * root[i * MO + o];
  agg[idx] = s;
}

// h_out = elu(agg_prev); agg_next = bias + h_out @ root
template<int MI, int MO>
__global__ __launch_bounds__(256) void elu_node_kernel(
    const float* __restrict__ agg_prev, const float* __restrict__ root,
    const float* __restrict__ bias, float* __restrict__ hout, float* __restrict__ agg_next){
  __shared__ float hl[32][MI + 1];
  int n0 = blockIdx.x * 32;
  int t  = threadIdx.x;
  for (int idx = t; idx < 32 * MI; idx += 256){
    int nl = idx / MI, i = idx - nl * MI;
    float v = eluf(agg_prev[(size_t)(n0 + nl) * MI + i]);
    hl[nl][i] = v;
    hout[(size_t)(n0 + nl) * MI + i] = v;
  }
  __syncthreads();
  for (int idx = t; idx < 32 * MO; idx += 256){
    int nl = idx / MO, o = idx - nl * MO;
    float s = bias[o];
    #pragma unroll 8
    for (int i = 0; i < MI; ++i) s += hl[nl][i] * root[i * MO + o];
    agg_next[(size_t)(n0 + nl) * MO + o] = s;
  }
}

// ---- MFMA edge kernel: 4 waves/WG = 4 K-quarters, 64 edges/WG ----
// Each wave: 64 edges x MO cols x quarter-K. Partials combined via LDS overlay;
// atomic work split per-m-fragment across waves. depth-2 B prefetch, A hoisted.
template<int MIR, int MIP, int MO, int HIDK>
__global__ __launch_bounds__(256, 3) void edge_mfma(
    const float* __restrict__ ea, const float* __restrict__ w1, const float* __restrict__ b1,
    const _Float16* __restrict__ bt, const float* __restrict__ h, int ldh,
    const int* __restrict__ src, const int* __restrict__ dst, float* __restrict__ agg)
{
  constexpr int NF   = MO / 16;
  constexpr int NBLK = MIP / 8;
  constexpr int KS   = (HIDK * MIP) / 32;          // 36 / 132 / 260 (even)
  constexpr int HIDP = HIDK;                       // even
  constexpr int HID_B  = 64 * HIDP * 2;
  constexpr int HS_B   = 64 * MIP * 2;
  constexpr int COMB_B = 4 * 3 * NF * 64 * 16;     // m x s x n x lane x 16B
  constexpr int EA_O   = HID_B + HS_B;
  constexpr int SRC_O  = EA_O + 1280;
  constexpr int STG_E  = SRC_O + 256;
  constexpr int DST_O  = (STG_E > COMB_B) ? STG_E : COMB_B;

  __shared__ __align__(16) char pool[DST_O + 256];
  _Float16* hidp = (_Float16*)pool;
  _Float16* hsp  = (_Float16*)(pool + HID_B);
  float*    eap  = (float*)(pool + EA_O);
  int*      src_l = (int*)(pool + SRC_O);
  int*      dst_l = (int*)(pool + DST_O);

  const int tid  = threadIdx.x;
  const int lane = tid & 63;
  const int wave = tid >> 6;           // K-quarter id
  const int c15  = lane & 15;
  const int g    = lane >> 4;
  const int e0   = blockIdx.x * 64;

  // K-quarter boundaries, rounded up to even ks
  const int ksb = ((KS * wave / 4) + 1) & ~1;
  const int kse = ((KS * (wave + 1) / 4) + 1) & ~1;
  const int KSW = kse - ksb;

  // phase 0: stage tile data
  for (int t = tid; t < 320; t += 256) eap[t] = ea[(size_t)e0 * 5 + t];
  if (tid < 64){ src_l[tid] = src[e0 + tid]; dst_l[tid] = dst[e0 + tid]; }
  __syncthreads();

  // phase 1: hid rows [0, HIDK) = relu(ea@w1+b1); row 128 = 1 (bias), rows >128 = 0
  for (int t = tid; t < 64 * HIDK; t += 256){
    int e = t / HIDK, k = t - e * HIDK;
    float s;
    if (k < 128){
      s = b1[k];
      #pragma unroll
      for (int j = 0; j < 5; ++j) s += eap[e * 5 + j] * w1[j * 128 + k];
      s = fmaxf(s, 0.f);
    } else s = (k == 128) ? 1.f : 0.f;
    hidp[e * HIDP + k] = (_Float16)s;
  }
  // gather h_src (float4 vectorized, f16, zero-pad i>=MIR), block-swizzled
  constexpr int IV = MIP / 4;
  for (int t = tid; t < 64 * IV; t += 256){
    int e = t / IV, i4 = (t - e * IV) * 4;
    f32x4 hv4 = *(const f32x4*)&h[(size_t)src_l[e] * ldh + i4];
    _Float16 o4[4];
    #pragma unroll
    for (int q = 0; q < 4; ++q) o4[q] = (i4 + q < MIR) ? (_Float16)hv4[q] : (_Float16)0.f;
    int bw = ((i4 >> 3) ^ (e & (NBLK - 1)));
    *(f16x4*)&hsp[e * MIP + ((bw << 3) | (i4 & 7))] = *(const f16x4*)o4;
  }
  __syncthreads();

  const f16x8* __restrict__ btv = (const f16x8*)bt;
  int er_[4];
  #pragma unroll
  for (int m = 0; m < 4; ++m) er_[m] = m * 16 + c15;

  f32x4 acc[4][NF];
  #pragma unroll
  for (int m = 0; m < 4; ++m)
    #pragma unroll
    for (int n = 0; n < NF; ++n) acc[m][n] = (f32x4){0.f, 0.f, 0.f, 0.f};

  // A hoist
  f16x8 hsh[4][2];
  #pragma unroll
  for (int m = 0; m < 4; ++m){
    const int er = er_[m];
    if constexpr (MIP == 8){
      hsh[m][0] = *(const f16x8*)&hsp[er * MIP];
      hsh[m][1] = hsh[m][0];
    } else if constexpr (MIP == 32){
      int blk = g ^ (er & 3);
      hsh[m][0] = *(const f16x8*)&hsp[er * MIP + (blk << 3)];
      hsh[m][1] = hsh[m][0];
    } else {
      int b0 = g ^ (er & 7), b1x = (4 + g) ^ (er & 7);
      hsh[m][0] = *(const f16x8*)&hsp[er * MIP + (b0 << 3)];
      hsh[m][1] = *(const f16x8*)&hsp[er * MIP + (b1x << 3)];
    }
  }

  // B prologue: depth-2 ping-pong
  f16x8 bqA[NF], bqB[NF];
  #pragma unroll
  for (int n = 0; n < NF; ++n){
    bqA[n] = btv[((size_t)(ksb + 0) * NF + n) * 64 + lane];
    bqB[n] = btv[((size_t)(ksb + 1) * NF + n) * 64 + lane];
  }

#define EDGE_SUB(U, BQ)                                                         \
  {                                                                             \
    _Pragma("unroll")                                                           \
    for (int m = 0; m < 4; ++m){                                                \
      _Float16 hv;                                                              \
      f16x8 hs8;                                                                \
      if constexpr (MIP == 64){ hv = hvS[m]; hs8 = hsh[m][(U)]; }               \
      else if constexpr (MIP == 32){ hv = hv2[m][(U)]; hs8 = hsh[m][0]; }       \
      else { hv = hidp[er_[m] * HIDP + ((ksb + u + (U)) << 2) + g];             \
             hs8 = hsh[m][0]; }                                                 \
      f16x8 hvv = {hv, hv, hv, hv, hv, hv, hv, hv};                             \
      f16x8 av  = hs8 * hvv;                                                    \
      _Pragma("unroll")                                                         \
      for (int n = 0; n < NF; ++n)                                              \
        acc[m][n] = __builtin_amdgcn_mfma_f32_16x16x32_f16(av, BQ[n],           \
                                                           acc[m][n], 0, 0, 0);\
    }                                                                           \
    _Pragma("unroll")                                                           \
    for (int n = 0; n < NF; ++n)                                                \
      BQ[n] = btv[((size_t)(ksb + u + (U) + 2) * NF + n) * 64 + lane];          \
  }

  for (int u = 0; u < KSW; u += 2){
    _Float16 hvS[4]; f16x2 hv2[4];
    if constexpr (MIP == 64){
      #pragma unroll
      for (int m = 0; m < 4; ++m) hvS[m] = hidp[er_[m] * HIDP + ((ksb + u) >> 1)];
    } else if constexpr (MIP == 32){
      #pragma unroll
      for (int m = 0; m < 4; ++m) hv2[m] = *(const f16x2*)&hidp[er_[m] * HIDP + (ksb + u)];
    }
    (void)hvS; (void)hv2;
    EDGE_SUB(0, bqA)
    EDGE_SUB(1, bqB)
  }
#undef EDGE_SUB

  // combine K-quarters via LDS overlay (hid/hs/ea/src are dead after this barrier)
  __syncthreads();
  float* comb = (float*)pool;
  #pragma unroll
  for (int m = 0; m < 4; ++m){
    if (m != wave){
      int s = wave - (wave > m ? 1 : 0);
      #pragma unroll
      for (int n = 0; n < NF; ++n)
        *(f32x4*)&comb[(((m * 3 + s) * NF + n) * 64 + lane) * 4] = acc[m][n];
    }
  }
  __syncthreads();
  // wave w reduces + atomics its own m-fragment (16 edges x MO cols)
  #pragma unroll
  for (int m = 0; m < 4; ++m){
    if (m == wave){
      #pragma unroll
      for (int n = 0; n < NF; ++n){
        #pragma unroll
        for (int s = 0; s < 3; ++s)
          acc[m][n] += *(const f32x4*)&comb[(((m * 3 + s) * NF + n) * 64 + lane) * 4];
        #pragma unroll
        for (int j = 0; j < 4; ++j){
          int er = m * 16 + (g << 2) + j;
          atomicAdd(&agg[(size_t)dst_l[er] * MO + n * 16 + c15], acc[m][n][j]);
        }
      }
    }
  }
}

__global__ void zero_kernel(float* __restrict__ p, int n){
  int i = blockIdx.x * blockDim.x + threadIdx.x;
  if (i < n) p[i] = 0.f;
}

// pool with fused elu on the conv output
__global__ void pool_kernel(const float* __restrict__ agg3, const float* __restrict__ x,
                            const int* __restrict__ batch,
                            float* __restrict__ sums, float* __restrict__ cnts){
  int idx = blockIdx.x * blockDim.x + threadIdx.x;
  if (idx >= Nn * 75) return;
  int n = idx / 75, f = idx - n * 75;
  float v = (f < 64) ? eluf(agg3[(size_t)n * 64 + f]) : x[(size_t)n * 16 + 5 + (f - 64)];
  int b = batch[n];
  atomicAdd(&sums[(size_t)b * 75 + f], v);
  if (f == 0) atomicAdd(&cnts[b], 1.f);
}

__global__ __launch_bounds__(64) void head_kernel(
    const float* __restrict__ sums, const float* __restrict__ cnts,
    const float* __restrict__ fc1w, const float* __restrict__ fc1b,
    const float* __restrict__ fc2w, const float* __restrict__ fc2b,
    const float* __restrict__ fc3w, const float* __restrict__ fc3b,
    float* __restrict__ out)
{
  __shared__ float m[64][77];
  __shared__ float a1[64][33];
  __shared__ float a2[64][17];
  int t = threadIdx.x;
  int g = blockIdx.x * 64 + t;
  bool ok = g < Gg;
  float c = ok ? fmaxf(cnts[g], 1.f) : 1.f;
  for (int f = 0; f < 75; ++f) m[t][f] = ok ? sums[(size_t)g * 75 + f] / c : 0.f;
  for (int j = 0; j < 32; ++j){
    float s = fc1b[j];
    for (int f = 0; f < 75; ++f) s += m[t][f] * fc1w[f * 32 + j];
    a1[t][j] = eluf(s);
  }
  for (int j = 0; j < 16; ++j){
    float s = fc2b[j];
    for (int i = 0; i < 32; ++i) s += a1[t][i] * fc2w[i * 16 + j];
    a2[t][j] = eluf(s);
  }
  float s = fc3b[0];
  for (int i = 0; i < 16; ++i) s += a2[t][i] * fc3w[i];
  if (ok) out[g] = s;
}

extern "C" void kernel_launch(void* const* d_in, const int* in_sizes, int n_in,
                              void* d_out, int out_size, void* d_ws, size_t ws_size,
                              hipStream_t stream)
{
  (void)in_sizes; (void)n_in; (void)out_size; (void)ws_size;
  const float* x     = (const float*)d_in[0];
  const int*   ei    = (const int*)d_in[1];
  const float* ea    = (const float*)d_in[2];
  const int*   batch = (const int*)d_in[3];
  const float* cw1[3]   = {(const float*)d_in[4],  (const float*)d_in[10], (const float*)d_in[16]};
  const float* cb1[3]   = {(const float*)d_in[5],  (const float*)d_in[11], (const float*)d_in[17]};
  const float* cw2[3]   = {(const float*)d_in[6],  (const float*)d_in[12], (const float*)d_in[18]};
  const float* cb2[3]   = {(const float*)d_in[7],  (const float*)d_in[13], (const float*)d_in[19]};
  const float* croot[3] = {(const float*)d_in[8],  (const float*)d_in[14], (const float*)d_in[20]};
  const float* cbias[3] = {(const float*)d_in[9],  (const float*)d_in[15], (const float*)d_in[21]};
  const float* fc1w = (const float*)d_in[22];
  const float* fc1b = (const float*)d_in[23];
  const float* fc2w = (const float*)d_in[24];
  const float* fc2b = (const float*)d_in[25];
  const float* fc3w = (const float*)d_in[26];
  const float* fc3b = (const float*)d_in[27];
  float* out = (float*)d_out;

  float* ws   = (float*)d_ws;
  float* h    = ws;                              // N*64
  float* aggA = h + (size_t)Nn * 64;             // N*64
  float* aggB = aggA + (size_t)Nn * 64;          // N*64
  float* sums = aggB + (size_t)Nn * 64;          // G*75
  float* cnts = sums + (size_t)Gg * 75;          // G
  _Float16* bt1 = (_Float16*)(cnts + Gg);        // 2*(36+4)*512  = 40960
  _Float16* bt2 = bt1 + 40960;                   // 4*(132+4)*512 = 278528
  _Float16* bt3 = bt2 + 278528;                  // 4*(260+4)*512 = 540672

  const int* src = ei;
  const int* dst = ei + Ee;

  bt_all<<<3280, 256, 0, stream>>>(cw2[0], cb2[0], cw2[1], cb2[1], cw2[2], cb2[2], bt1, bt2, bt3);

  // ---- layer 1: MI=5 (pad 8), MO=32; h = x (stride 16) ----
  node_kernel<5, 32><<<(Nn * 32 + 255) / 256, 256, 0, stream>>>(x, 16, croot[0], cbias[0], aggA);
  edge_mfma<5, 8, 32, 144><<<Ee / 64, 256, 0, stream>>>(ea, cw1[0], cb1[0], bt1, x, 16, src, dst, aggA);

  // ---- layer 2: MI=32, MO=64 ----
  elu_node_kernel<32, 64><<<(Nn + 31) / 32, 256, 0, stream>>>(aggA, croot[1], cbias[1], h, aggB);
  edge_mfma<32, 32, 64, 132><<<Ee / 64, 256, 0, stream>>>(ea, cw1[1], cb1[1], bt2, h, 32, src, dst, aggB);

  // ---- layer 3: MI=64, MO=64 ----
  elu_node_kernel<64, 64><<<(Nn + 31) / 32, 256, 0, stream>>>(aggB, croot[2], cbias[2], h, aggA);
  edge_mfma<64, 64, 64, 130><<<Ee / 64, 256, 0, stream>>>(ea, cw1[2], cb1[2], bt3, h, 64, src, dst, aggA);

  // ---- pooling (fused elu) + head ----
  zero_kernel<<<(Gg * 76 + 255) / 256, 256, 0, stream>>>(sums, Gg * 76);
  pool_kernel<<<(Nn * 75 + 255) / 256, 256, 0, stream>>>(aggA, x, batch, sums, cnts);
  head_kernel<<<(Gg + 63) / 64, 64, 0, stream>>>(sums, cnts, fc1w, fc1b, fc2w, fc2b, fc3w, fc3b, out);
}

// Round 10
// 221.913 us; speedup vs baseline: 1.7681x; 1.1969x over previous
//
#include <hip/hip_runtime.h>
#include <math.h>

constexpr int Nn = 20000;
constexpr int Ee = 80000;
constexpr int Gg = 1000;

typedef _Float16 f16x8 __attribute__((ext_vector_type(8)));
typedef _Float16 f16x4 __attribute__((ext_vector_type(4)));
typedef _Float16 f16x2 __attribute__((ext_vector_type(2)));
typedef float    f32x4 __attribute__((ext_vector_type(4)));

__device__ __forceinline__ float eluf(float x){ return x > 0.f ? x : (expf(x) - 1.f); }

// ---- fused B permute for all 3 layers (ks-major fragment layout) ----
// bt[((ks*NF + n)*64 + l)*8 + j] = B[ks*32 + (l>>4)*8 + j][n*16 + (l&15)]
__device__ __forceinline__ void bt_emit(int idx, int lgNF, int MIR, int s, int MO,
                                        const float* __restrict__ w2,
                                        const float* __restrict__ b2,
                                        _Float16* __restrict__ bt){
  int NF = 1 << lgNF;
  int j  = idx & 7;
  int l  = (idx >> 3) & 63;
  int n  = (idx >> 9) & (NF - 1);
  int ks = idx >> (9 + lgNF);
  int col = n * 16 + (l & 15);
  int kk  = ks * 32 + ((l >> 4) << 3) + j;
  int k = kk >> s, i = kk & ((1 << s) - 1);
  float v = 0.f;
  if (i < MIR){
    if (k < 128)       v = w2[(size_t)k * (MIR * MO) + i * MO + col];
    else if (k == 128) v = b2[i * MO + col];
  }
  bt[idx] = (_Float16)v;
}

__global__ void bt_all(const float* __restrict__ w21, const float* __restrict__ b21,
                       const float* __restrict__ w22, const float* __restrict__ b22,
                       const float* __restrict__ w23, const float* __restrict__ b23,
                       _Float16* __restrict__ bt1, _Float16* __restrict__ bt2,
                       _Float16* __restrict__ bt3){
  int idx = blockIdx.x * 256 + threadIdx.x;
  if (idx < 36864)                 bt_emit(idx,                1, 5,  3, 32, w21, b21, bt1);
  else if (idx < 36864 + 270336)   bt_emit(idx - 36864,        2, 32, 5, 64, w22, b22, bt2);
  else if (idx < 839680)           bt_emit(idx - 307200,       2, 64, 6, 64, w23, b23, bt3);
}

// agg[n,o] = bias[o] + sum_i h[n,i]*root[i,o]   (h has row stride ldh)
template<int MI, int MO>
__global__ void node_kernel(const float* __restrict__ h, int ldh,
                            const float* __restrict__ root,
                            const float* __restrict__ bias, float* __restrict__ agg){
  int idx = blockIdx.x * blockDim.x + threadIdx.x;
  if (idx >= Nn * MO) return;
  int n = idx / MO, o = idx - n * MO;
  float s = bias[o];
  #pragma unroll
  for (int i = 0; i < MI; ++i) s += h[(size_t)n * ldh + i] * root[i * MO + o];
  agg[idx] = s;
}

// h_out = elu(agg_prev); agg_next = bias + h_out @ root
template<int MI, int MO>
__global__ __launch_bounds__(256) void elu_node_kernel(
    const float* __restrict__ agg_prev, const float* __restrict__ root,
    const float* __restrict__ bias, float* __restrict__ hout, float* __restrict__ agg_next){
  __shared__ float hl[32][MI + 1];
  int n0 = blockIdx.x * 32;
  int t  = threadIdx.x;
  for (int idx = t; idx < 32 * MI; idx += 256){
    int nl = idx / MI, i = idx - nl * MI;
    float v = eluf(agg_prev[(size_t)(n0 + nl) * MI + i]);
    hl[nl][i] = v;
    hout[(size_t)(n0 + nl) * MI + i] = v;
  }
  __syncthreads();
  for (int idx = t; idx < 32 * MO; idx += 256){
    int nl = idx / MO, o = idx - nl * MO;
    float s = bias[o];
    #pragma unroll 8
    for (int i = 0; i < MI; ++i) s += hl[nl][i] * root[i * MO + o];
    agg_next[(size_t)(n0 + nl) * MO + o] = s;
  }
}

// ---- MFMA edge kernel: 4 waves/WG = 4 K-quarters, 64 edges/WG ----
// hv (hid) reads software-pipelined one 4-U block ahead; phased LDS combine.
template<int MIR, int MIP, int MO, int HIDK, int LB>
__global__ __launch_bounds__(256, LB) void edge_mfma(
    const float* __restrict__ ea, const float* __restrict__ w1, const float* __restrict__ b1,
    const _Float16* __restrict__ bt, const float* __restrict__ h, int ldh,
    const int* __restrict__ src, const int* __restrict__ dst, float* __restrict__ agg)
{
  constexpr int NF   = MO / 16;
  constexpr int NBLK = MIP / 8;
  constexpr int KS   = (HIDK * MIP) / 32;          // 36 / 132 / 260
  constexpr int HIDP = (MIP == 8) ? 148 : ((MIP == 32) ? 140 : 136); // padded for prefetch
  constexpr int HID_B  = 64 * HIDP * 2;
  constexpr int HS_B   = 64 * MIP * 2;
  constexpr int COMB_B = 2 * 3 * NF * 64 * 16;     // phased overlay: 2 m x 3 s x n x lane x 16B
  constexpr int EA_O   = HID_B + HS_B;
  constexpr int SRC_O  = EA_O + 1280;
  constexpr int STG_E  = SRC_O + 256;
  constexpr int DST_O  = (STG_E > COMB_B) ? STG_E : COMB_B;

  __shared__ __align__(16) char pool[DST_O + 256];
  _Float16* hidp = (_Float16*)pool;
  _Float16* hsp  = (_Float16*)(pool + HID_B);
  float*    eap  = (float*)(pool + EA_O);
  int*      src_l = (int*)(pool + SRC_O);
  int*      dst_l = (int*)(pool + DST_O);

  const int tid  = threadIdx.x;
  const int lane = tid & 63;
  const int wave = tid >> 6;           // K-quarter id
  const int c15  = lane & 15;
  const int g    = lane >> 4;
  const int e0   = blockIdx.x * 64;

  // K-quarter boundaries, rounded up to multiple of 4
  const int ksb = ((KS * wave / 4) + 3) & ~3;
  const int kse = (wave == 3) ? KS : ((KS * (wave + 1) / 4) + 3) & ~3;
  const int KSW = kse - ksb;

  // phase 0: stage tile data
  for (int t = tid; t < 320; t += 256) eap[t] = ea[(size_t)e0 * 5 + t];
  if (tid < 64){ src_l[tid] = src[e0 + tid]; dst_l[tid] = dst[e0 + tid]; }
  __syncthreads();

  // phase 1: hid rows [0, HIDK) = relu(ea@w1+b1); row 128 = 1 (bias), rows >128 = 0
  for (int t = tid; t < 64 * HIDK; t += 256){
    int e = t / HIDK, k = t - e * HIDK;
    float s;
    if (k < 128){
      s = b1[k];
      #pragma unroll
      for (int j = 0; j < 5; ++j) s += eap[e * 5 + j] * w1[j * 128 + k];
      s = fmaxf(s, 0.f);
    } else s = (k == 128) ? 1.f : 0.f;
    hidp[e * HIDP + k] = (_Float16)s;
  }
  // gather h_src (float4 vectorized, f16, zero-pad i>=MIR), block-swizzled
  constexpr int IV = MIP / 4;
  for (int t = tid; t < 64 * IV; t += 256){
    int e = t / IV, i4 = (t - e * IV) * 4;
    f32x4 hv4 = *(const f32x4*)&h[(size_t)src_l[e] * ldh + i4];
    _Float16 o4[4];
    #pragma unroll
    for (int q = 0; q < 4; ++q) o4[q] = (i4 + q < MIR) ? (_Float16)hv4[q] : (_Float16)0.f;
    int bw = ((i4 >> 3) ^ (e & (NBLK - 1)));
    *(f16x4*)&hsp[e * MIP + ((bw << 3) | (i4 & 7))] = *(const f16x4*)o4;
  }
  __syncthreads();

  const f16x8* __restrict__ btv = (const f16x8*)bt;
  int er_[4];
  #pragma unroll
  for (int m = 0; m < 4; ++m) er_[m] = m * 16 + c15;

  f32x4 acc[4][NF];
  #pragma unroll
  for (int m = 0; m < 4; ++m)
    #pragma unroll
    for (int n = 0; n < NF; ++n) acc[m][n] = (f32x4){0.f, 0.f, 0.f, 0.f};

  // A hoist
  f16x8 hsh[4][2];
  #pragma unroll
  for (int m = 0; m < 4; ++m){
    const int er = er_[m];
    if constexpr (MIP == 8){
      hsh[m][0] = *(const f16x8*)&hsp[er * MIP];
      hsh[m][1] = hsh[m][0];
    } else if constexpr (MIP == 32){
      int blk = g ^ (er & 3);
      hsh[m][0] = *(const f16x8*)&hsp[er * MIP + (blk << 3)];
      hsh[m][1] = hsh[m][0];
    } else {
      int b0 = g ^ (er & 7), b1x = (4 + g) ^ (er & 7);
      hsh[m][0] = *(const f16x8*)&hsp[er * MIP + (b0 << 3)];
      hsh[m][1] = *(const f16x8*)&hsp[er * MIP + (b1x << 3)];
    }
  }

  // B prologue: depth-2 ping-pong
  f16x8 bqA[NF], bqB[NF];
  #pragma unroll
  for (int n = 0; n < NF; ++n){
    bqA[n] = btv[((size_t)(ksb + 0) * NF + n) * 64 + lane];
    bqB[n] = btv[((size_t)(ksb + 1) * NF + n) * 64 + lane];
  }

#define EDGE_SUB(U, BQ)                                                         \
  {                                                                             \
    _Pragma("unroll")                                                           \
    for (int m = 0; m < 4; ++m){                                                \
      _Float16 hv;                                                              \
      f16x8 hs8;                                                                \
      if constexpr (MIP == 64){ hv = hvC2[m][(U) >> 1]; hs8 = hsh[m][(U) & 1]; }\
      else if constexpr (MIP == 32){ hv = hvC4[m][(U)]; hs8 = hsh[m][0]; }      \
      else { hv = hidp[er_[m] * HIDP + ((ksb + u + (U)) << 2) + g];             \
             hs8 = hsh[m][0]; }                                                 \
      f16x8 hvv = {hv, hv, hv, hv, hv, hv, hv, hv};                             \
      f16x8 av  = hs8 * hvv;                                                    \
      _Pragma("unroll")                                                         \
      for (int n = 0; n < NF; ++n)                                              \
        acc[m][n] = __builtin_amdgcn_mfma_f32_16x16x32_f16(av, BQ[n],           \
                                                           acc[m][n], 0, 0, 0);\
    }                                                                           \
    _Pragma("unroll")                                                           \
    for (int n = 0; n < NF; ++n)                                                \
      BQ[n] = btv[((size_t)(ksb + u + (U) + 2) * NF + n) * 64 + lane];          \
  }

  // hv pipeline registers (only the MIP-matching set is used)
  f16x2 hvC2[4], hvN2[4];
  f16x4 hvC4[4], hvN4[4];
  if constexpr (MIP == 64){
    #pragma unroll
    for (int m = 0; m < 4; ++m)
      hvC2[m] = *(const f16x2*)&hidp[er_[m] * HIDP + (ksb >> 1)];
  } else if constexpr (MIP == 32){
    #pragma unroll
    for (int m = 0; m < 4; ++m)
      hvC4[m] = *(const f16x4*)&hidp[er_[m] * HIDP + ksb];
  }

  for (int u = 0; u < KSW; u += 4){
    if constexpr (MIP == 64){
      #pragma unroll
      for (int m = 0; m < 4; ++m)
        hvN2[m] = *(const f16x2*)&hidp[er_[m] * HIDP + ((ksb + u + 4) >> 1)];
    } else if constexpr (MIP == 32){
      #pragma unroll
      for (int m = 0; m < 4; ++m)
        hvN4[m] = *(const f16x4*)&hidp[er_[m] * HIDP + (ksb + u + 4)];
    }
    __builtin_amdgcn_s_setprio(1);
    EDGE_SUB(0, bqA)
    EDGE_SUB(1, bqB)
    EDGE_SUB(2, bqA)
    EDGE_SUB(3, bqB)
    __builtin_amdgcn_s_setprio(0);
    #pragma unroll
    for (int m = 0; m < 4; ++m){ hvC2[m] = hvN2[m]; hvC4[m] = hvN4[m]; }
  }
#undef EDGE_SUB

  // ---- phased combine: round A (m=0,1), round B (m=2,3), then parallel atomics ----
  __syncthreads();
  float* comb = (float*)pool;
  #pragma unroll
  for (int m = 0; m < 2; ++m) if (m != wave){
    int s = wave - (wave > m ? 1 : 0);
    #pragma unroll
    for (int n = 0; n < NF; ++n)
      *(f32x4*)&comb[(((m * 3 + s) * NF + n) * 64 + lane) * 4] = acc[m][n];
  }
  __syncthreads();
  #pragma unroll
  for (int m = 0; m < 2; ++m) if (m == wave){
    #pragma unroll
    for (int n = 0; n < NF; ++n)
      #pragma unroll
      for (int s = 0; s < 3; ++s)
        acc[m][n] += *(const f32x4*)&comb[(((m * 3 + s) * NF + n) * 64 + lane) * 4];
  }
  __syncthreads();
  #pragma unroll
  for (int m = 2; m < 4; ++m) if (m != wave){
    int s = wave - (wave > m ? 1 : 0);
    #pragma unroll
    for (int n = 0; n < NF; ++n)
      *(f32x4*)&comb[((((m - 2) * 3 + s) * NF + n) * 64 + lane) * 4] = acc[m][n];
  }
  __syncthreads();
  #pragma unroll
  for (int m = 2; m < 4; ++m) if (m == wave){
    #pragma unroll
    for (int n = 0; n < NF; ++n)
      #pragma unroll
      for (int s = 0; s < 3; ++s)
        acc[m][n] += *(const f32x4*)&comb[((((m - 2) * 3 + s) * NF + n) * 64 + lane) * 4];
  }
  // all waves atomic their own m-fragment in parallel
  #pragma unroll
  for (int m = 0; m < 4; ++m) if (m == wave){
    #pragma unroll
    for (int n = 0; n < NF; ++n)
      #pragma unroll
      for (int j = 0; j < 4; ++j){
        int er = m * 16 + (g << 2) + j;
        atomicAdd(&agg[(size_t)dst_l[er] * MO + n * 16 + c15], acc[m][n][j]);
      }
  }
}

// ---- fused mean-pool + head MLP: one 64-thread WG per graph (batch is sorted) ----
__global__ __launch_bounds__(64) void pool_head_kernel(
    const float* __restrict__ agg3, const float* __restrict__ x,
    const int* __restrict__ batch,
    const float* __restrict__ fc1w, const float* __restrict__ fc1b,
    const float* __restrict__ fc2w, const float* __restrict__ fc2b,
    const float* __restrict__ fc3w, const float* __restrict__ fc3b,
    float* __restrict__ out)
{
  int gph  = blockIdx.x;
  int lane = threadIdx.x;
  // segment [start, end): lower_bound(gph), lower_bound(gph+1) over sorted batch
  int lo = 0, hi = Nn;
  while (lo < hi){ int mid = (lo + hi) >> 1; if (batch[mid] < gph) lo = mid + 1; else hi = mid; }
  int start = lo;
  hi = Nn;
  while (lo < hi){ int mid = (lo + hi) >> 1; if (batch[mid] < gph + 1) lo = mid + 1; else hi = mid; }
  int end = lo;

  float s0 = 0.f, s1 = 0.f;
  for (int n = start; n < end; ++n){
    s0 += eluf(agg3[(size_t)n * 64 + lane]);
    if (lane < 11) s1 += x[(size_t)n * 16 + 5 + lane];
  }
  float inv = 1.f / fmaxf((float)(end - start), 1.f);

  __shared__ float m[75];
  __shared__ float a1[32];
  __shared__ float a2[16];
  m[lane] = s0 * inv;
  if (lane < 11) m[64 + lane] = s1 * inv;
  __syncthreads();
  if (lane < 32){
    float s = fc1b[lane];
    for (int f = 0; f < 75; ++f) s += m[f] * fc1w[f * 32 + lane];
    a1[lane] = eluf(s);
  }
  __syncthreads();
  if (lane < 16){
    float s = fc2b[lane];
    #pragma unroll
    for (int i = 0; i < 32; ++i) s += a1[i] * fc2w[i * 16 + lane];
    a2[lane] = eluf(s);
  }
  __syncthreads();
  if (lane == 0){
    float s = fc3b[0];
    #pragma unroll
    for (int i = 0; i < 16; ++i) s += a2[i] * fc3w[i];
    out[gph] = s;
  }
}

extern "C" void kernel_launch(void* const* d_in, const int* in_sizes, int n_in,
                              void* d_out, int out_size, void* d_ws, size_t ws_size,
                              hipStream_t stream)
{
  (void)in_sizes; (void)n_in; (void)out_size; (void)ws_size;
  const float* x     = (const float*)d_in[0];
  const int*   ei    = (const int*)d_in[1];
  const float* ea    = (const float*)d_in[2];
  const int*   batch = (const int*)d_in[3];
  const float* cw1[3]   = {(const float*)d_in[4],  (const float*)d_in[10], (const float*)d_in[16]};
  const float* cb1[3]   = {(const float*)d_in[5],  (const float*)d_in[11], (const float*)d_in[17]};
  const float* cw2[3]   = {(const float*)d_in[6],  (const float*)d_in[12], (const float*)d_in[18]};
  const float* cb2[3]   = {(const float*)d_in[7],  (const float*)d_in[13], (const float*)d_in[19]};
  const float* croot[3] = {(const float*)d_in[8],  (const float*)d_in[14], (const float*)d_in[20]};
  const float* cbias[3] = {(const float*)d_in[9],  (const float*)d_in[15], (const float*)d_in[21]};
  const float* fc1w = (const float*)d_in[22];
  const float* fc1b = (const float*)d_in[23];
  const float* fc2w = (const float*)d_in[24];
  const float* fc2b = (const float*)d_in[25];
  const float* fc3w = (const float*)d_in[26];
  const float* fc3b = (const float*)d_in[27];
  float* out = (float*)d_out;

  float* ws   = (float*)d_ws;
  float* h    = ws;                              // N*64
  float* aggA = h + (size_t)Nn * 64;             // N*64
  float* aggB = aggA + (size_t)Nn * 64;          // N*64
  _Float16* bt1 = (_Float16*)(aggB + (size_t)Nn * 64);  // 2*(36+4)*512  = 40960
  _Float16* bt2 = bt1 + 40960;                   // 4*(132+4)*512 = 278528
  _Float16* bt3 = bt2 + 278528;                  // 4*(260+4)*512 = 540672

  const int* src = ei;
  const int* dst = ei + Ee;

  bt_all<<<3280, 256, 0, stream>>>(cw2[0], cb2[0], cw2[1], cb2[1], cw2[2], cb2[2], bt1, bt2, bt3);

  // ---- layer 1: MI=5 (pad 8), MO=32; h = x (stride 16) ----
  node_kernel<5, 32><<<(Nn * 32 + 255) / 256, 256, 0, stream>>>(x, 16, croot[0], cbias[0], aggA);
  edge_mfma<5, 8, 32, 144, 4><<<Ee / 64, 256, 0, stream>>>(ea, cw1[0], cb1[0], bt1, x, 16, src, dst, aggA);

  // ---- layer 2: MI=32, MO=64 ----
  elu_node_kernel<32, 64><<<(Nn + 31) / 32, 256, 0, stream>>>(aggA, croot[1], cbias[1], h, aggB);
  edge_mfma<32, 32, 64, 132, 3><<<Ee / 64, 256, 0, stream>>>(ea, cw1[1], cb1[1], bt2, h, 32, src, dst, aggB);

  // ---- layer 3: MI=64, MO=64 ----
  elu_node_kernel<64, 64><<<(Nn + 31) / 32, 256, 0, stream>>>(aggB, croot[2], cbias[2], h, aggA);
  edge_mfma<64, 64, 64, 130, 3><<<Ee / 64, 256, 0, stream>>>(ea, cw1[2], cb1[2], bt3, h, 64, src, dst, aggA);

  // ---- fused mean-pool + head ----
  pool_head_kernel<<<Gg, 64, 0, stream>>>(aggA, x, batch, fc1w, fc1b, fc2w, fc2b, fc3w, fc3b, out);
}